// Round 4
// baseline (155.726 us; speedup 1.0000x reference)
//
#include <hip/hip_runtime.h>

#define BB 32
#define LL 4096
#define DD 512
#define NUM 32
#define KK 5

typedef float f32x4 __attribute__((ext_vector_type(4)));

// lags = trunc(linspace(1, 168, 32)) -- precomputed, verified margins >= 0.03
__device__ __constant__ int d_LAGS[NUM] = {
    1, 6, 11, 17, 22, 27, 33, 38, 44, 49, 54, 60, 65, 71, 76, 81,
    87, 92, 97, 103, 108, 114, 119, 124, 130, 135, 141, 146, 151, 157, 162, 168};

// ---------------- Kernel 1: row means over D ----------------
// One wave (64 lanes) per row; 4 rows per 256-thread block.
// Regular (caching) loads on purpose: this pass populates L3 with x so the
// combine pass's gather reads hit the Infinity Cache.
__global__ __launch_bounds__(256) void k_mean(const float* __restrict__ x,
                                              float* __restrict__ xm) {
    int row  = blockIdx.x * 4 + (threadIdx.x >> 6);   // [0, B*L)
    int lane = threadIdx.x & 63;
    const float* p = x + (size_t)row * DD;
    f32x4 a = *reinterpret_cast<const f32x4*>(p + 4 * lane);
    f32x4 b = *reinterpret_cast<const f32x4*>(p + 4 * lane + 256);
    float s = (a.x + a.y) + (a.z + a.w) + (b.x + b.y) + (b.z + b.w);
#pragma unroll
    for (int off = 32; off > 0; off >>= 1) s += __shfl_down(s, off, 64);
    if (lane == 0) xm[row] = s * (1.0f / DD);
}

// ---------------- Kernel 2: scores + top-5 + weights, one block per batch ----
// Stage the 16 KB x_mean row in LDS; wave w computes lags {4q + w}; thread 0
// does the serial top-5 (tie-break smallest index = lax.top_k semantics).
__global__ __launch_bounds__(256) void k_scores_topk(const float* __restrict__ xm,
                                                     float* __restrict__ w,
                                                     int* __restrict__ sel) {
    __shared__ float row[LL];    // 16 KB
    __shared__ float sc[NUM];
    int b = blockIdx.x;
    for (int i = threadIdx.x; i < LL; i += 256) row[i] = xm[b * LL + i];
    __syncthreads();

    int wid = threadIdx.x >> 6, lane = threadIdx.x & 63;
#pragma unroll
    for (int q = 0; q < 8; ++q) {
        int k   = q * 4 + wid;
        int lag = d_LAGS[k];
        int n   = LL - lag;
        float s = 0.0f;
        for (int t = lane; t < n; t += 64) s += row[t] * row[t + lag];
#pragma unroll
        for (int off = 32; off > 0; off >>= 1) s += __shfl_down(s, off, 64);
        if (lane == 0) sc[k] = s / (float)n;
    }
    __syncthreads();

    if (threadIdx.x == 0) {
        float v[NUM];
#pragma unroll
        for (int i = 0; i < NUM; i++) v[i] = sc[i];
        float vals[KK];
        int   idx[KK];
#pragma unroll
        for (int j = 0; j < KK; j++) {
            float best = -INFINITY;
            int bi = 0;
#pragma unroll
            for (int i = 0; i < NUM; i++) {
                if (v[i] > best) { best = v[i]; bi = i; }
            }
            vals[j] = best;
            idx[j]  = bi;
            v[bi]   = -INFINITY;
        }
        float sum = 0.0f;
#pragma unroll
        for (int j = 0; j < KK; j++) sum += vals[j];
        float den = sum + 1e-6f;
#pragma unroll
        for (int j = 0; j < KK; j++) {
            w[b * KK + j]   = vals[j] / den;
            sel[b * KK + j] = d_LAGS[idx[j]];
        }
    }
}

// ---------------- Kernel 3: weighted sum of 5 rolls ----------------
// 512-thread block = 4 consecutive output rows; thread handles a float4 at
// d = 4*(tid&127). XCD-contiguous swizzle: each of the 8 XCDs owns 4096
// consecutive quads (= 4 whole batches), so the 5 lagged source rows
// (span <= 168 rows = 336 KB) stay in that XCD's L2.
// Weights/lags are block-uniform -> plain global loads broadcast; no LDS,
// no barrier. Output stores NON-TEMPORAL so x (256 MiB = L3 capacity) stays
// L3-resident across passes and graph replays.
__global__ __launch_bounds__(512) void k_combine(const float* __restrict__ x,
                                                 const float* __restrict__ w,
                                                 const int* __restrict__ sel,
                                                 float* __restrict__ out) {
    unsigned bid = blockIdx.x;                        // [0, B*L/4)
    const unsigned QUADS_PER_XCD = (BB * LL / 4) / 8; // 4096
    unsigned qid = (bid & 7u) * QUADS_PER_XCD + (bid >> 3);
    unsigned r   = qid * 4 + (threadIdx.x >> 7);      // output row [0, B*L)
    int b = (int)(r >> 12);      // / 4096
    int t = (int)(r & 4095u);    // % 4096

    float ww[KK];
    int   lg[KK];
#pragma unroll
    for (int j = 0; j < KK; j++) {
        ww[j] = w[b * KK + j];
        lg[j] = sel[b * KK + j];
    }

    const float* xb = x + (size_t)b * (LL * DD);
    int d4 = threadIdx.x & 127;
    f32x4 acc = {0.f, 0.f, 0.f, 0.f};
#pragma unroll
    for (int j = 0; j < KK; j++) {
        int src = (t - lg[j]) & (LL - 1);   // roll(+lag): out[t] = x[(t-lag) mod L]
        f32x4 v = *reinterpret_cast<const f32x4*>(xb + (size_t)src * DD + 4 * d4);
        float wj = ww[j];
        acc.x += wj * v.x;
        acc.y += wj * v.y;
        acc.z += wj * v.z;
        acc.w += wj * v.w;
    }
    __builtin_nontemporal_store(acc,
        reinterpret_cast<f32x4*>(out + (size_t)r * DD + 4 * d4));
}

extern "C" void kernel_launch(void* const* d_in, const int* in_sizes, int n_in,
                              void* d_out, int out_size, void* d_ws, size_t ws_size,
                              hipStream_t stream) {
    const float* x = (const float*)d_in[0];
    float* out = (float*)d_out;

    // workspace layout (all fp32/int32, < 1 MB total)
    char* ws = (char*)d_ws;
    float* xm  = (float*)(ws);                                  // B*L floats = 512 KB
    float* wts = (float*)(ws + (size_t)BB * LL * 4);            // B*K floats
    int*   sel = (int*)  (ws + (size_t)BB * LL * 4 + BB * KK * 4);

    k_mean<<<(BB * LL) / 4, 256, 0, stream>>>(x, xm);
    k_scores_topk<<<BB, 256, 0, stream>>>(xm, wts, sel);
    k_combine<<<(BB * LL) / 4, 512, 0, stream>>>(x, wts, sel, out);
}

// Round 5
// 133.957 us; speedup vs baseline: 1.1625x; 1.1625x over previous
//
#include <hip/hip_runtime.h>

#define BB 32
#define LL 4096
#define DD 512
#define NUM 32
#define KK 5

typedef float f32x4 __attribute__((ext_vector_type(4)));

// lags = trunc(linspace(1, 168, 32)) -- precomputed, verified margins >= 0.03
__device__ __constant__ int d_LAGS[NUM] = {
    1, 6, 11, 17, 22, 27, 33, 38, 44, 49, 54, 60, 65, 71, 76, 81,
    87, 92, 97, 103, 108, 114, 119, 124, 130, 135, 141, 146, 151, 157, 162, 168};

// ---------------- Kernel 1: row means over D ----------------
// One wave (64 lanes) per row; 4 rows per 256-thread block.
// Regular (caching) loads on purpose: this pass populates L3 with x so the
// combine pass's gather reads hit the Infinity Cache.
__global__ __launch_bounds__(256) void k_mean(const float* __restrict__ x,
                                              float* __restrict__ xm) {
    int row  = blockIdx.x * 4 + (threadIdx.x >> 6);   // [0, B*L)
    int lane = threadIdx.x & 63;
    const float* p = x + (size_t)row * DD;
    f32x4 a = *reinterpret_cast<const f32x4*>(p + 4 * lane);
    f32x4 b = *reinterpret_cast<const f32x4*>(p + 4 * lane + 256);
    float s = (a.x + a.y) + (a.z + a.w) + (b.x + b.y) + (b.z + b.w);
#pragma unroll
    for (int off = 32; off > 0; off >>= 1) s += __shfl_down(s, off, 64);
    if (lane == 0) xm[row] = s * (1.0f / DD);
}

// ---------------- Kernel 2: autocorrelation scores ----------------
// One block per (batch, lag-candidate); 1024 blocks -> enough TLP to hide
// global-load latency (R4 lesson: the 32-block fused version was latency-bound).
__global__ __launch_bounds__(256) void k_scores(const float* __restrict__ xm,
                                                float* __restrict__ scores) {
    int b   = blockIdx.x >> 5;   // / NUM
    int k   = blockIdx.x & 31;   // % NUM
    int lag = d_LAGS[k];
    const float* row = xm + b * LL;
    int n = LL - lag;
    float s = 0.0f;
    for (int t = threadIdx.x; t < n; t += 256) s += row[t] * row[t + lag];
#pragma unroll
    for (int off = 32; off > 0; off >>= 1) s += __shfl_down(s, off, 64);
    __shared__ float red[4];
    int wid = threadIdx.x >> 6, lane = threadIdx.x & 63;
    if (lane == 0) red[wid] = s;
    __syncthreads();
    if (threadIdx.x == 0) {
        float tot = (red[0] + red[1]) + (red[2] + red[3]);
        scores[blockIdx.x] = tot / (float)n;
    }
}

// ---------------- Kernel 3: per-batch top-5 + weights ----------------
// One thread per batch (B=32). Tie-break: smallest index (lax.top_k semantics).
__global__ __launch_bounds__(64) void k_topk(const float* __restrict__ scores,
                                             float* __restrict__ w,
                                             int* __restrict__ sel) {
    int b = threadIdx.x;
    if (b >= BB) return;
    float sc[NUM];
#pragma unroll
    for (int i = 0; i < NUM; i++) sc[i] = scores[b * NUM + i];
    float vals[KK];
    int idx[KK];
#pragma unroll
    for (int j = 0; j < KK; j++) {
        float best = -INFINITY;
        int bi = 0;
#pragma unroll
        for (int i = 0; i < NUM; i++) {
            if (sc[i] > best) { best = sc[i]; bi = i; }
        }
        vals[j] = best;
        idx[j]  = bi;
        sc[bi]  = -INFINITY;
    }
    float sum = 0.0f;
#pragma unroll
    for (int j = 0; j < KK; j++) sum += vals[j];
    float den = sum + 1e-6f;
#pragma unroll
    for (int j = 0; j < KK; j++) {
        w[b * KK + j]   = vals[j] / den;
        sel[b * KK + j] = d_LAGS[idx[j]];
    }
}

// ---------------- Kernel 4: weighted sum of 5 rolls ----------------
// 256-thread block = 2 consecutive output rows (b,t),(b,t+1); thread handles a
// float4 at d = 4*(tid&127). XCD-contiguous swizzle: each of the 8 XCDs owns
// 16384 consecutive rows (= 4 whole batches), so the 5 lagged source rows
// (span <= 168 rows = 336 KB) stay in that XCD's L2.
// Output stores are NON-TEMPORAL: they bypass L2/L3 so x (exactly 256 MiB =
// Infinity Cache capacity) stays L3-resident -> combine reads hit L3, and in
// steady-state graph replay the mean pass's reads hit L3 too.
__global__ __launch_bounds__(256) void k_combine(const float* __restrict__ x,
                                                 const float* __restrict__ w,
                                                 const int* __restrict__ sel,
                                                 float* __restrict__ out) {
    unsigned bid = blockIdx.x;                          // [0, B*L/2)
    const unsigned PAIRS_PER_XCD = (BB * LL / 2) / 8;   // 8192
    unsigned pid = (bid & 7u) * PAIRS_PER_XCD + (bid >> 3);
    unsigned r   = pid * 2 + (threadIdx.x >> 7);        // output row [0, B*L)
    int b = (int)(r >> 12);      // / 4096
    int t = (int)(r & 4095u);    // % 4096

    __shared__ float ww[KK];
    __shared__ int   llag[KK];
    if (threadIdx.x < KK) {
        ww[threadIdx.x]   = w[b * KK + threadIdx.x];
        llag[threadIdx.x] = sel[b * KK + threadIdx.x];
    }
    __syncthreads();

    const float* xb = x + (size_t)b * (LL * DD);
    int d4 = threadIdx.x & 127;
    f32x4 acc = {0.f, 0.f, 0.f, 0.f};
#pragma unroll
    for (int j = 0; j < KK; j++) {
        int src = (t - llag[j]) & (LL - 1);   // roll(+lag): out[t] = x[(t-lag) mod L]
        f32x4 v = *reinterpret_cast<const f32x4*>(xb + (size_t)src * DD + 4 * d4);
        float wj = ww[j];
        acc.x += wj * v.x;
        acc.y += wj * v.y;
        acc.z += wj * v.z;
        acc.w += wj * v.w;
    }
    __builtin_nontemporal_store(acc,
        reinterpret_cast<f32x4*>(out + (size_t)r * DD + 4 * d4));
}

extern "C" void kernel_launch(void* const* d_in, const int* in_sizes, int n_in,
                              void* d_out, int out_size, void* d_ws, size_t ws_size,
                              hipStream_t stream) {
    const float* x = (const float*)d_in[0];
    float* out = (float*)d_out;

    // workspace layout (all fp32/int32, < 1 MB total)
    char* ws = (char*)d_ws;
    float* xm     = (float*)(ws);                         // B*L floats   = 512 KB
    float* scores = (float*)(ws + (size_t)BB * LL * 4);   // B*NUM floats = 4 KB
    float* wts    = (float*)(ws + (size_t)BB * LL * 4 + BB * NUM * 4);        // B*K
    int*   sel    = (int*)  (ws + (size_t)BB * LL * 4 + BB * NUM * 4 + BB * KK * 4);

    k_mean<<<(BB * LL) / 4, 256, 0, stream>>>(x, xm);
    k_scores<<<BB * NUM, 256, 0, stream>>>(xm, scores);
    k_topk<<<1, 64, 0, stream>>>(scores, wts, sel);
    k_combine<<<(BB * LL) / 2, 256, 0, stream>>>(x, wts, sel, out);
}